// Round 3
// baseline (363.760 us; speedup 1.0000x reference)
//
#include <hip/hip_runtime.h>
#include <math.h>

#define N_NODES 100000
#define N_RELS  3
#define N_EDGES 400000
#define D       128
#define NTOT    (N_RELS * N_NODES)          // 300000
#define SCAN_BLK 293                        // ceil(300000/1024)

typedef __attribute__((ext_vector_type(8))) short bf16x8;
typedef __attribute__((ext_vector_type(4))) float f32x4;

static __device__ __forceinline__ ushort f2bf(float f) {
    uint u = __builtin_bit_cast(uint, f);
    u = u + 0x7fffu + ((u >> 16) & 1u);   // round-to-nearest-even
    return (ushort)(u >> 16);
}
static __device__ __forceinline__ float bf_lo(uint u) {
    return __builtin_bit_cast(float, u << 16);
}
static __device__ __forceinline__ float bf_hi(uint u) {
    return __builtin_bit_cast(float, u & 0xffff0000u);
}

// W transpose + bf16 convert: Wt[r][j][k] = bf16(W[r][k][j]); bsum[j] = mean_r b[r][j]
__global__ void prep_w_kernel(const float* __restrict__ W, const float* __restrict__ b,
                              ushort* __restrict__ Wt, float* __restrict__ bsum) {
    int id = blockIdx.x * 256 + threadIdx.x;
    if (id < 3 * D * D) {
        int r = id >> 14;
        int rem = id & 16383;
        int k = rem >> 7, j = rem & 127;
        Wt[r * 16384 + j * 128 + k] = f2bf(W[id]);
    }
    if (blockIdx.x == 0 && threadIdx.x < D) {
        int j = threadIdx.x;
        bsum[j] = (b[j] + b[D + j] + b[2 * D + j]) * (1.0f / 3.0f);
    }
}

// Pass 1: degree histograms (both directions).
__global__ void deg_kernel(const int* __restrict__ edges,
                           int* __restrict__ deg_out, int* __restrict__ deg_in) {
    int e = blockIdx.x * 256 + threadIdx.x;
    int rel = blockIdx.y;
    if (e >= N_EDGES) return;
    int s = edges[(size_t)(rel * 2 + 0) * N_EDGES + e];
    int t = edges[(size_t)(rel * 2 + 1) * N_EDGES + e];
    atomicAdd(deg_out + rel * N_NODES + s, 1);
    atomicAdd(deg_in + rel * N_NODES + t, 1);
}

// Scan step 1: per-block (1024 elems) sums of deg_in.
__global__ void scan1_kernel(const int* __restrict__ deg_in, int* __restrict__ block_sums) {
    __shared__ int red[4];
    int i0 = blockIdx.x * 1024 + threadIdx.x * 4;
    int s = 0;
    if (i0 + 3 < NTOT) {
        int4 v = *(const int4*)(deg_in + i0);
        s = v.x + v.y + v.z + v.w;
    } else {
        for (int k = 0; k < 4; ++k) if (i0 + k < NTOT) s += deg_in[i0 + k];
    }
    #pragma unroll
    for (int off = 32; off >= 1; off >>= 1) s += __shfl_xor(s, off);
    if ((threadIdx.x & 63) == 0) red[threadIdx.x >> 6] = s;
    __syncthreads();
    if (threadIdx.x == 0) block_sums[blockIdx.x] = red[0] + red[1] + red[2] + red[3];
}

// Scan step 2: exclusive scan of block sums (single block).
__global__ void scan2_kernel(int* __restrict__ block_sums) {
    __shared__ int sm[512];
    int t = threadIdx.x;
    int v = (t < SCAN_BLK) ? block_sums[t] : 0;
    sm[t] = v;
    __syncthreads();
    for (int off = 1; off < 512; off <<= 1) {
        int add = (t >= off) ? sm[t - off] : 0;
        __syncthreads();
        sm[t] += add;
        __syncthreads();
    }
    if (t < SCAN_BLK) block_sums[t] = sm[t] - v;   // exclusive
}

// Scan step 3: per-element exclusive scan -> row_start & cursor; also rsqrt degrees.
__global__ void scan3_kernel(const int* __restrict__ deg_in, const int* __restrict__ deg_out,
                             const int* __restrict__ block_sums,
                             int* __restrict__ row_start, int* __restrict__ cursor,
                             float* __restrict__ rdi, float* __restrict__ rdo) {
    __shared__ int sm[256];
    int t = threadIdx.x;
    int i0 = blockIdx.x * 1024 + t * 4;
    int v[4] = {0, 0, 0, 0};
    if (i0 + 3 < NTOT) {
        int4 q = *(const int4*)(deg_in + i0);
        v[0] = q.x; v[1] = q.y; v[2] = q.z; v[3] = q.w;
    } else {
        for (int k = 0; k < 4; ++k) if (i0 + k < NTOT) v[k] = deg_in[i0 + k];
    }
    int s = v[0] + v[1] + v[2] + v[3];
    sm[t] = s;
    __syncthreads();
    for (int off = 1; off < 256; off <<= 1) {
        int add = (t >= off) ? sm[t - off] : 0;
        __syncthreads();
        sm[t] += add;
        __syncthreads();
    }
    int base = block_sums[blockIdx.x] + sm[t] - s;
    int pre = 0;
    for (int k = 0; k < 4; ++k) {
        int i = i0 + k;
        if (i < NTOT) {
            int rs = base + pre;
            row_start[i] = rs;
            cursor[i] = rs;
            rdi[i] = rsqrtf((float)max(v[k], 1));
            rdo[i] = rsqrtf((float)max(deg_out[i], 1));
        }
        pre += v[k];
    }
}

// Pass 2: CSR fill — dense scatter into 4.8 MB adjacency array.
__global__ void fill_kernel(const int* __restrict__ edges, int* __restrict__ cursor,
                            int* __restrict__ adj) {
    int e = blockIdx.x * 256 + threadIdx.x;
    int rel = blockIdx.y;
    if (e >= N_EDGES) return;
    int s = edges[(size_t)(rel * 2 + 0) * N_EDGES + e];
    int t = edges[(size_t)(rel * 2 + 1) * N_EDGES + e];
    int p = atomicAdd(cursor + rel * N_NODES + t, 1);
    adj[p] = s;
}

// h[n, rel*128+j] = bf16( rdo[rel][n] * sum_k x[n,k] W[rel][k][j] )
// 2-pass bf16 split on A (x); W single bf16. 256 thr = 4 waves (2x2), 128x128 tile.
__global__ __launch_bounds__(256) void gemm_h_kernel(
    const float* __restrict__ x, const ushort* __restrict__ Wt,
    const float* __restrict__ rdo, ushort* __restrict__ h) {
    __shared__ ushort Bt[128 * 128];
    const int rel = blockIdx.x;
    const int n0  = blockIdx.y * 128;
    const int tid = threadIdx.x;

    {
        const ushort* Wg = Wt + rel * 16384;
        #pragma unroll
        for (int c = 0; c < 8; ++c) {
            int id = c * 256 + tid;
            int j = id >> 4, k8 = id & 15;
            uint4 v = *(const uint4*)(Wg + j * 128 + k8 * 8);
            int ba = (j * 256 + k8 * 16) ^ ((j & 7) << 4);
            *(uint4*)((char*)Bt + ba) = v;
        }
    }
    __syncthreads();

    const int w = tid >> 6, l = tid & 63;
    const int wrow = (w >> 1) * 64, wcol = (w & 1) * 64;
    const int lr = l & 15, lk = (l >> 4) * 8;

    f32x4 acc[4][4];
    #pragma unroll
    for (int fi = 0; fi < 4; ++fi)
        #pragma unroll
        for (int fj = 0; fj < 4; ++fj)
            acc[fi][fj] = (f32x4){0.f, 0.f, 0.f, 0.f};

    #pragma unroll
    for (int ks = 0; ks < 4; ++ks) {
        bf16x8 bfr[4];
        #pragma unroll
        for (int fj = 0; fj < 4; ++fj) {
            int j = wcol + fj * 16 + lr;
            int ba = (j * 256 + (ks * 32 + lk) * 2) ^ ((j & 7) << 4);
            bfr[fj] = *(bf16x8*)((char*)Bt + ba);
        }
        #pragma unroll
        for (int fi = 0; fi < 4; ++fi) {
            int row = n0 + wrow + fi * 16 + lr;
            row = min(row, N_NODES - 1);
            const float* xp = x + (size_t)row * 128 + ks * 32 + lk;
            float4 va = *(const float4*)xp;
            float4 vb = *(const float4*)(xp + 4);
            float fs[8] = {va.x, va.y, va.z, va.w, vb.x, vb.y, vb.z, vb.w};
            bf16x8 ah, al;
            #pragma unroll
            for (int q = 0; q < 8; ++q) {
                ushort hq = f2bf(fs[q]);
                float hf = __builtin_bit_cast(float, (uint)hq << 16);
                ah[q] = (short)hq;
                al[q] = (short)f2bf(fs[q] - hf);
            }
            #pragma unroll
            for (int fj = 0; fj < 4; ++fj) {
                acc[fi][fj] = __builtin_amdgcn_mfma_f32_16x16x32_bf16(ah, bfr[fj], acc[fi][fj], 0, 0, 0);
                acc[fi][fj] = __builtin_amdgcn_mfma_f32_16x16x32_bf16(al, bfr[fj], acc[fi][fj], 0, 0, 0);
            }
        }
    }

    const int cr4 = (l >> 4) * 4;
    #pragma unroll
    for (int fi = 0; fi < 4; ++fi) {
        int rbase = n0 + wrow + fi * 16 + cr4;
        float sc[4];
        #pragma unroll
        for (int i = 0; i < 4; ++i) {
            int row = rbase + i;
            sc[i] = (row < N_NODES) ? rdo[rel * N_NODES + row] : 0.f;
        }
        #pragma unroll
        for (int fj = 0; fj < 4; ++fj) {
            int col = wcol + fj * 16 + lr;
            #pragma unroll
            for (int i = 0; i < 4; ++i) {
                int row = rbase + i;
                if (row < N_NODES)
                    h[(size_t)row * 384 + rel * 128 + col] = f2bf(acc[fi][fj][i] * sc[i]);
            }
        }
    }
}

// out[n,:] = (1/3) sum_r rdi_r[n] * sum_{e in CSR row} h[src_e, r*128:(r+1)*128] + bsum
__global__ __launch_bounds__(256) void gather_kernel(
    const ushort* __restrict__ h, const int* __restrict__ row_start,
    const int* __restrict__ deg_in, const int* __restrict__ adj,
    const float* __restrict__ rdi, const float* __restrict__ bsum,
    float* __restrict__ out) {
    int w = threadIdx.x >> 6, l = threadIdx.x & 63;
    int n = blockIdx.x * 4 + w;
    if (n >= N_NODES) return;
    float ox = 0.f, oy = 0.f;
    #pragma unroll
    for (int r = 0; r < 3; ++r) {
        int base = r * N_NODES + n;
        int start = row_start[base];
        int cnt = deg_in[base];
        float ax = 0.f, ay = 0.f;
        for (int c0 = 0; c0 < cnt; c0 += 64) {
            int m = min(cnt - c0, 64);
            int e = 0;
            if (l < m) e = adj[start + c0 + l];
            int i = 0;
            for (; i + 2 <= m; i += 2) {
                int s0 = __shfl(e, i), s1 = __shfl(e, i + 1);
                uint u0 = *(const uint*)(h + (size_t)s0 * 384 + r * 128 + 2 * l);
                uint u1 = *(const uint*)(h + (size_t)s1 * 384 + r * 128 + 2 * l);
                ax += bf_lo(u0); ay += bf_hi(u0);
                ax += bf_lo(u1); ay += bf_hi(u1);
            }
            if (i < m) {
                int s0 = __shfl(e, i);
                uint u0 = *(const uint*)(h + (size_t)s0 * 384 + r * 128 + 2 * l);
                ax += bf_lo(u0); ay += bf_hi(u0);
            }
        }
        float sc = rdi[base];
        ox = fmaf(ax, sc, ox);
        oy = fmaf(ay, sc, oy);
    }
    float2 bs = *(const float2*)(bsum + 2 * l);
    float2 o;
    o.x = ox * (1.f / 3.f) + bs.x;
    o.y = oy * (1.f / 3.f) + bs.y;
    *(float2*)(out + (size_t)n * 128 + 2 * l) = o;
}

extern "C" void kernel_launch(void* const* d_in, const int* in_sizes, int n_in,
                              void* d_out, int out_size, void* d_ws, size_t ws_size,
                              hipStream_t stream) {
    const float* x     = (const float*)d_in[0];
    const int*   edges = (const int*)d_in[1];   // [R][2][E] int32
    const float* W     = (const float*)d_in[2]; // [R][D][D]
    const float* b     = (const float*)d_in[3]; // [R][D]
    float* out = (float*)d_out;

    char* ws = (char*)d_ws;
    size_t off = 0;
    auto alloc = [&](size_t bytes) -> void* {
        void* p = ws + off;
        off += (bytes + 255) & ~(size_t)255;
        return p;
    };
    int*   deg_out   = (int*)alloc((size_t)NTOT * 4);
    int*   deg_in    = (int*)alloc((size_t)NTOT * 4);
    size_t zero_bytes = off;                       // memset deg_out + deg_in
    int*   cursor    = (int*)alloc((size_t)NTOT * 4);
    int*   row_start = (int*)alloc((size_t)NTOT * 4);
    float* rdo       = (float*)alloc((size_t)NTOT * 4);
    float* rdi       = (float*)alloc((size_t)NTOT * 4);
    float* bsum      = (float*)alloc((size_t)D * 4);
    int*   block_sums= (int*)alloc(512 * 4);
    ushort* Wt       = (ushort*)alloc((size_t)3 * D * D * 2);
    int*   adj       = (int*)alloc((size_t)N_RELS * N_EDGES * 4);
    ushort* h        = (ushort*)alloc((size_t)N_NODES * 3 * D * 2);

    hipMemsetAsync(ws, 0, zero_bytes, stream);
    prep_w_kernel<<<192, 256, 0, stream>>>(W, b, Wt, bsum);
    deg_kernel<<<dim3((N_EDGES + 255) / 256, 3), 256, 0, stream>>>(edges, deg_out, deg_in);
    scan1_kernel<<<SCAN_BLK, 256, 0, stream>>>(deg_in, block_sums);
    scan2_kernel<<<1, 512, 0, stream>>>(block_sums);
    scan3_kernel<<<SCAN_BLK, 256, 0, stream>>>(deg_in, deg_out, block_sums,
                                               row_start, cursor, rdi, rdo);
    fill_kernel<<<dim3((N_EDGES + 255) / 256, 3), 256, 0, stream>>>(edges, cursor, adj);
    gemm_h_kernel<<<dim3(3, (N_NODES + 127) / 128), 256, 0, stream>>>(x, Wt, rdo, h);
    gather_kernel<<<(N_NODES + 3) / 4, 256, 0, stream>>>(h, row_start, deg_in, adj,
                                                         rdi, bsum, out);
}